// Round 4
// baseline (333.923 us; speedup 1.0000x reference)
//
#include <hip/hip_runtime.h>
#include <cstdint>

// LeNet-5 forward, B=16384. Batch-lane design: lane = sample, wave-uniform
// control, [feature][N] SoA layouts (coalesced), f32-accum dot2 math, f16
// pair-packed storage, shifted-weight pairs (no alignbit).
// R10 = R9 (proven 322us) + cache-traffic cuts:
//  (a) c3s4 row-reuse: 2 blocks per oc (y2 012: rows 0-9 / y2 34: rows 6-13)
//      -> plane bytes read 105 -> 63 cells per oc*plane (/1.67), plane loads
//      issued as one burst. grid (nb/256, 32).
//  (b) uint2 pair-cells for xp/s4p/h5p/h6p (S2P already was): halves load
//      count + addressing in c1s2/c5/f6/rbf; k_tr writes coalesced uint2.
// Buffer sizes and plan offsets identical to R7/R9:
//   Plan A (ws >= 55,312,384): S2P @0 (38,535,168); XP @38,535,168
//     (16,777,216, front); S4P @38,535,168 (15,728,640, after front);
//     H5P @0 (3,932,160); H6P @4,194,304 (2,752,512). 10 dispatches.
//   Plan B: XP @0; S2P @16,777,216; S4P @0; H5P @7,864,320; H6P @9,830,400.
//     peak 36,044,800. 13 dispatches.
// Weight pack lives at d_out tail (k_rbf never reads it; k_rbf rewrites all
// of out after the pack's last consumer).

typedef unsigned int u32;

union U32H2 { u32 u; _Float16 h[2]; };
__device__ __forceinline__ float f16lo(u32 v) { U32H2 a; a.u = v; return (float)a.h[0]; }
__device__ __forceinline__ float f16hi(u32 v) { U32H2 a; a.u = v; return (float)a.h[1]; }
__device__ __forceinline__ u32 packh2(float a, float b) {
    U32H2 x; x.h[0] = (_Float16)a; x.h[1] = (_Float16)b; return x.u;
}

typedef _Float16 h2v __attribute__((ext_vector_type(2)));
union U32V2 { u32 u; h2v v; };

#if defined(__has_builtin)
#if __has_builtin(__builtin_amdgcn_fdot2)
#define HAVE_FDOT2 1
#endif
#endif

// c += a.h0*b.h0 + a.h1*b.h1  (f16 mul, f32 accumulate) -> v_dot2_f32_f16
__device__ __forceinline__ float dot2(u32 a, u32 b, float c) {
    U32V2 x, y; x.u = a; y.u = b;
#ifdef HAVE_FDOT2
    return __builtin_amdgcn_fdot2(x.v, y.v, c, false);
#else
    return c + (float)x.v[0] * (float)y.v[0] + (float)x.v[1] * (float)y.v[1];
#endif
}

// A*tanh(S*v), S=2/3: tanh(y) = 1 - 2/(exp(2y)+1), 2y = (4/3)v
__device__ __forceinline__ float tact(float v) {
    float e = __expf(1.3333333333f * v);
    return 1.7159f * (1.0f - 2.0f * __builtin_amdgcn_rcpf(e + 1.0f));
}

// C3 sparse connection lists (from reference CONNECTIONS)
__device__ const int C3_NIC[16] = {3,3,3,3,3,3, 4,4,4,4,4,4,4,4,4, 6};
__device__ const int C3_ICL[96] = {
    0,1,2,0,0,0,  1,2,3,0,0,0,  2,3,4,0,0,0,  3,4,5,0,0,0,
    0,4,5,0,0,0,  0,1,5,0,0,0,  0,1,2,3,0,0,  1,2,3,4,0,0,
    2,3,4,5,0,0,  0,3,4,5,0,0,  0,1,4,5,0,0,  0,1,2,5,0,0,
    0,1,3,4,0,0,  1,2,4,5,0,0,  0,2,3,5,0,0,  0,1,2,3,4,5 };

// Weight-pack layout (u32 indices inside WPK):
//  W1P  @0     : [6ch][5ky][3q]   pair = (w[2q], w[2q+1]|0)          (90, pad 96)
//  W1S  @96    : [6ch][5ky][3q]   pair = (0,w0)|(w1,w2)|(w3,w4)      (90, pad 96)
//  W3P  @192   : [96 plane][5][3] aligned                            (1440)
//  W3S  @1632  : [96 plane][5][3] shifted                            (1440)
//  W5P  @3072  : [120c][80g][3q]  pair = (w5[c][g*5+2q], +1|0)       (28800)
//  F6P  @31872 : [84o][60i]       pair = (f6w[o][2i], f6w[o][2i+1])  (5040)
#define WPK_W1  0
#define WPK_W1S 96
#define WPK_W3  192
#define WPK_W3S 1632
#define WPK_W5  3072
#define WPK_F6  31872
#define WPK_N   36912

__global__ __launch_bounds__(256) void k_wpack(
    const float* __restrict__ w1, const float* __restrict__ w3,
    const float* __restrict__ w5, const float* __restrict__ f6w,
    u32* __restrict__ wpk)
{
    const int idx = blockIdx.x * 256 + threadIdx.x;
    if (idx >= WPK_N) return;
    float a = 0.0f, b = 0.0f;
    if (idx < 192) {                         // w1 aligned / shifted
        const int s = idx >= 96;
        const int t = idx - s * 96;
        if (t < 90) {
            int ch = t / 15, r = t % 15, ky = r / 3, q = r % 3;
            const float* w = w1 + ch * 25 + ky * 5;
            if (!s) { a = w[2 * q]; if (q < 2) b = w[2 * q + 1]; }
            else if (q == 0) { b = w[0]; }
            else { a = w[2 * q - 1]; b = w[2 * q]; }
        }
    } else if (idx < WPK_W5) {               // w3 aligned / shifted
        const int s = (idx - WPK_W3) >= 1440;
        const int t = idx - WPK_W3 - s * 1440;
        int p = t / 15, r = t % 15, ky = r / 3, q = r % 3;
        const float* w = w3 + p * 25 + ky * 5;
        if (!s) { a = w[2 * q]; if (q < 2) b = w[2 * q + 1]; }
        else if (q == 0) { b = w[0]; }
        else { a = w[2 * q - 1]; b = w[2 * q]; }
    } else if (idx < WPK_F6) {
        int t = idx - WPK_W5;
        int c = t / 240, r = t % 240, g = r / 3, q = r % 3;
        a = w5[c * 400 + g * 5 + 2 * q];
        if (q < 2) b = w5[c * 400 + g * 5 + 2 * q + 1];
    } else {
        int t = idx - WPK_F6;
        int o = t / 60, i = t % 60;
        a = f6w[o * 120 + 2 * i];
        b = f6w[o * 120 + 2 * i + 1];
    }
    wpk[idx] = packh2(a, b);
}

// ---------------- transpose: x chunk (8192,1024) f32 -> xp cells ------------
// xp as uint2[256][8192]: cell P, sample s holds f16 positions 4P..4P+3
// (pos-pairs 2P, 2P+1). grid (128, 16). Coalesced 8B writes.
__global__ __launch_bounds__(256) void k_tr(const float* __restrict__ x,
                                            u32* __restrict__ xp)
{
    __shared__ _Float16 lds[64 * 66];
    const int t = threadIdx.x;
    const int tb = blockIdx.x * 64;          // sample tile
    const int tp = blockIdx.y * 64;          // position tile
    #pragma unroll
    for (int i = 0; i < 16; ++i) {           // coalesced read along positions
        int idx = i * 256 + t;
        int bl = idx >> 6, pl = idx & 63;
        lds[pl * 66 + bl] = (_Float16)x[(size_t)(tb + bl) * 1024 + tp + pl];
    }
    __syncthreads();
    #pragma unroll
    for (int j = 0; j < 4; ++j) {            // cell writes along batch
        int idx = j * 256 + t;
        int pc = idx >> 6, bl = idx & 63;    // pc in [0,16): cell within tile
        U32H2 u0, u1;
        u0.h[0] = lds[(4 * pc + 0) * 66 + bl];
        u0.h[1] = lds[(4 * pc + 1) * 66 + bl];
        u1.h[0] = lds[(4 * pc + 2) * 66 + bl];
        u1.h[1] = lds[(4 * pc + 3) * 66 + bl];
        uint2 o; o.x = u0.u; o.y = u1.u;
        ((uint2*)xp)[(size_t)(blockIdx.y * 16 + pc) * 8192 + tb + bl] = o;
    }
}

// ---------------- C1 + S2 fused, grid (32, 42) ------------------------------
// blockIdx.y = oy2*3 + chpair. S2P: adjacent-column pairs in [fh][N][2] u32
// cells (as R9). xp read as uint2 cells: window row y0+r, col-pair c lives in
// cell (y0+r)*8 + (c>>1), comp c&1. Odd conv cols via shifted weight pairs.
__global__ __launch_bounds__(256) void k_c1s2(
    const u32* __restrict__ xp, const u32* __restrict__ wpk,
    const float* __restrict__ b1,
    const float* __restrict__ s2w, const float* __restrict__ s2b,
    u32* __restrict__ s2p, int ostr)
{
    const int sl = blockIdx.x * 256 + threadIdx.x;
    const int oy2 = blockIdx.y / 3;
    const int cp  = blockIdx.y % 3;          // channels 2cp, 2cp+1
    const int y0 = 2 * oy2;
    const uint2* xb = (const uint2*)xp + sl;

    u32 wl[2][15], wls[2][15];               // aligned + shifted pairs (uniform)
    #pragma unroll
    for (int a = 0; a < 2; ++a) {
        #pragma unroll
        for (int i = 0; i < 15; ++i) wl[a][i]  = wpk[WPK_W1  + (2 * cp + a) * 15 + i];
        #pragma unroll
        for (int i = 0; i < 15; ++i) wls[a][i] = wpk[WPK_W1S + (2 * cp + a) * 15 + i];
    }

    u32 cur[6][4];                           // aligned pairs, window cols 4qx..4qx+7
    #pragma unroll
    for (int r = 0; r < 6; ++r) {
        #pragma unroll
        for (int cc = 0; cc < 2; ++cc) {
            const uint2 v = xb[(size_t)((y0 + r) * 8 + cc) * 8192];
            cur[r][2 * cc] = v.x; cur[r][2 * cc + 1] = v.y;
        }
    }

    float va[2][7], vb[2][7];                // s2 row cols 0..6 / 7..13 per ch

    #pragma unroll
    for (int qx = 0; qx < 7; ++qx) {
        float o[2][2][4];
        #pragma unroll
        for (int a = 0; a < 2; ++a) {
            const float bbv = b1[2 * cp + a];
            #pragma unroll
            for (int u = 0; u < 2; ++u)
                #pragma unroll
                for (int d = 0; d < 4; ++d) o[a][u][d] = bbv;
        }
        #pragma unroll
        for (int r = 0; r < 6; ++r) {
            #pragma unroll
            for (int u = 0; u < 2; ++u) {
                const int ky = r - u;
                if (ky < 0 || ky > 4) continue;
                #pragma unroll
                for (int a = 0; a < 2; ++a) {
                    const u32 w0 = wl[a][ky * 3 + 0];
                    const u32 w1 = wl[a][ky * 3 + 1];
                    const u32 w2 = wl[a][ky * 3 + 2];
                    const u32 v0 = wls[a][ky * 3 + 0];
                    const u32 v1 = wls[a][ky * 3 + 1];
                    const u32 v2 = wls[a][ky * 3 + 2];
                    o[a][u][0] = dot2(cur[r][0], w0, dot2(cur[r][1], w1, dot2(cur[r][2], w2, o[a][u][0])));
                    o[a][u][1] = dot2(cur[r][0], v0, dot2(cur[r][1], v1, dot2(cur[r][2], v2, o[a][u][1])));
                    o[a][u][2] = dot2(cur[r][1], w0, dot2(cur[r][2], w1, dot2(cur[r][3], w2, o[a][u][2])));
                    o[a][u][3] = dot2(cur[r][1], v0, dot2(cur[r][2], v1, dot2(cur[r][3], v2, o[a][u][3])));
                }
            }
        }
        #pragma unroll
        for (int a = 0; a < 2; ++a) {
            const int ch = 2 * cp + a;
            const float sw = s2w[ch], sb = s2b[ch];
            float m0 = 0.25f * (tact(o[a][0][0]) + tact(o[a][0][1]) + tact(o[a][0][2]) + tact(o[a][0][3]));
            float m1 = 0.25f * (tact(o[a][1][0]) + tact(o[a][1][1]) + tact(o[a][1][2]) + tact(o[a][1][3]));
            va[a][qx] = tact(sw * m0 + sb);
            vb[a][qx] = tact(sw * m1 + sb);
        }
        if (qx < 6) {                        // slide: 1 uint2 per row (+2 pairs)
            #pragma unroll
            for (int r = 0; r < 6; ++r) {
                const uint2 v = xb[(size_t)((y0 + r) * 8 + qx + 2) * 8192];
                cur[r][0] = cur[r][2];
                cur[r][1] = cur[r][3];
                cur[r][2] = v.x;
                cur[r][3] = v.y;
            }
        }
    }
    // repack to adjacent-column pairs and store into [fh][ostr][2] cells
    #pragma unroll
    for (int a = 0; a < 2; ++a) {
        u32 o7[7];
        o7[0] = packh2(va[a][0], va[a][1]);
        o7[1] = packh2(va[a][2], va[a][3]);
        o7[2] = packh2(va[a][4], va[a][5]);
        o7[3] = packh2(va[a][6], vb[a][0]);
        o7[4] = packh2(vb[a][1], vb[a][2]);
        o7[5] = packh2(vb[a][3], vb[a][4]);
        o7[6] = packh2(vb[a][5], vb[a][6]);
        const int ch = 2 * cp + a;
        const int f0 = ch * 98 + oy2 * 7;    // parity = oy2&1 (uniform)
        const int fh0 = f0 >> 1;
        uint2* p2 = (uint2*)s2p;
        uint2 t;
        if ((oy2 & 1) == 0) {
            t.x = o7[0]; t.y = o7[1]; p2[(size_t)(fh0 + 0) * ostr + sl] = t;
            t.x = o7[2]; t.y = o7[3]; p2[(size_t)(fh0 + 1) * ostr + sl] = t;
            t.x = o7[4]; t.y = o7[5]; p2[(size_t)(fh0 + 2) * ostr + sl] = t;
            s2p[((size_t)(fh0 + 3) * ostr + sl) * 2] = o7[6];
        } else {
            s2p[((size_t)fh0 * ostr + sl) * 2 + 1] = o7[0];
            t.x = o7[1]; t.y = o7[2]; p2[(size_t)(fh0 + 1) * ostr + sl] = t;
            t.x = o7[3]; t.y = o7[4]; p2[(size_t)(fh0 + 2) * ostr + sl] = t;
            t.x = o7[5]; t.y = o7[6]; p2[(size_t)(fh0 + 3) * ostr + sl] = t;
        }
    }
}

// ---------------- C3 + S4 fused, grid (nb/256, 32) --------------------------
// blockIdx.y = oc*2 + half. half 0: y2 {0,1,2}, plane rows 0..9 (35 cells);
// half 1: y2 {3,4}, rows 6..13 (28 cells). Each plane's rows loaded ONCE and
// reused across the half's y2 values (traffic /1.67 vs per-(oc,y2) blocks).
// s4p feature g stored into pair cells: u32 addr ((g>>1)*nb+sl)*2 + (g&1).
__device__ __forceinline__ void emit_s4(
    const float a2[2][10], int oc, int y2, float swv, float sbv,
    u32* __restrict__ s4p, int nb, int sl)
{
    float tv[20];
    #pragma unroll
    for (int u = 0; u < 2; ++u)
        #pragma unroll
        for (int ox = 0; ox < 10; ++ox) tv[u * 10 + ox] = tact(a2[u][ox]);
    float so[5];
    #pragma unroll
    for (int x2 = 0; x2 < 5; ++x2)
        so[x2] = tact(0.25f * (tv[x2 * 4] + tv[x2 * 4 + 1] + tv[x2 * 4 + 2] + tv[x2 * 4 + 3]) * swv + sbv);
    const int g0 = (oc * 5 + y2) * 3;
    #pragma unroll
    for (int q = 0; q < 3; ++q) {
        const int g = g0 + q;
        const float lo = (q < 2) ? so[2 * q] : so[4];
        const float hi = (q < 2) ? so[2 * q + 1] : 0.0f;
        s4p[((size_t)(g >> 1) * nb + sl) * 2 + (g & 1)] = packh2(lo, hi);
    }
}

template<int NIC, int Y2_0, int NY2, int R0, int NCELL>
__device__ __forceinline__ void c3_half(
    const uint2* __restrict__ s2c, const u32* __restrict__ wpk,
    const int* __restrict__ icl, int oc, int nb, int sl,
    float a2[NY2][2][10])
{
    #pragma unroll
    for (int e = 0; e < NIC; ++e) {          // fully unrolled plane loop
        const int ic = icl[e];
        const uint2* sp = s2c + (size_t)(ic * 49 + (R0 * 7) / 2) * nb + sl;
        u32 wf[NCELL * 2];                   // rows R0..R0+NCELL*2/7-1
        #pragma unroll
        for (int k = 0; k < NCELL; ++k) {    // one burst of NCELL dwordx2
            const uint2 v = sp[(size_t)k * nb];
            wf[2 * k] = v.x; wf[2 * k + 1] = v.y;
        }
        u32 wl[15], wls[15];                 // uniform f16 weight pairs
        #pragma unroll
        for (int i = 0; i < 15; ++i) wl[i]  = wpk[WPK_W3  + (oc * 6 + ic) * 15 + i];
        #pragma unroll
        for (int i = 0; i < 15; ++i) wls[i] = wpk[WPK_W3S + (oc * 6 + ic) * 15 + i];
        #pragma unroll
        for (int y = 0; y < NY2; ++y) {
            #pragma unroll
            for (int r = 0; r < 6; ++r) {
                const u32* wa = wf + (2 * (Y2_0 + y) + r - R0) * 7;
                #pragma unroll
                for (int u = 0; u < 2; ++u) {
                    const int ky = r - u;
                    if (ky < 0 || ky > 4) continue;
                    const u32 w0 = wl[ky * 3 + 0];
                    const u32 w1 = wl[ky * 3 + 1];
                    const u32 w2 = wl[ky * 3 + 2];
                    const u32 v0 = wls[ky * 3 + 0];
                    const u32 v1 = wls[ky * 3 + 1];
                    const u32 v2 = wls[ky * 3 + 2];
                    #pragma unroll
                    for (int p = 0; p < 5; ++p) {
                        a2[y][u][2 * p]     = dot2(wa[p], w0, dot2(wa[p + 1], w1, dot2(wa[p + 2], w2, a2[y][u][2 * p])));
                        a2[y][u][2 * p + 1] = dot2(wa[p], v0, dot2(wa[p + 1], v1, dot2(wa[p + 2], v2, a2[y][u][2 * p + 1])));
                    }
                }
            }
        }
    }
}

__global__ __launch_bounds__(256) void k_c3s4(
    const u32* __restrict__ s2p, const u32* __restrict__ wpk,
    const float* __restrict__ b3, const float* __restrict__ s4w,
    const float* __restrict__ s4b, u32* __restrict__ s4p, int nb)
{
    const int sl = blockIdx.x * 256 + threadIdx.x;
    const int oc = blockIdx.y >> 1;
    const int hf = blockIdx.y & 1;
    const uint2* s2c = (const uint2*)s2p;
    const int* icl = &C3_ICL[oc * 6];
    const int nic = C3_NIC[oc];
    const float bbv = b3[oc];
    const float swv = s4w[oc], sbv = s4b[oc];

    if (hf == 0) {                           // y2 = 0,1,2; rows 0..9
        float a2[3][2][10];
        #pragma unroll
        for (int y = 0; y < 3; ++y)
            #pragma unroll
            for (int u = 0; u < 2; ++u)
                #pragma unroll
                for (int ox = 0; ox < 10; ++ox) a2[y][u][ox] = bbv;
        switch (nic) {                       // uniform scalar branch
            case 3:  c3_half<3, 0, 3, 0, 35>(s2c, wpk, icl, oc, nb, sl, a2); break;
            case 4:  c3_half<4, 0, 3, 0, 35>(s2c, wpk, icl, oc, nb, sl, a2); break;
            default: c3_half<6, 0, 3, 0, 35>(s2c, wpk, icl, oc, nb, sl, a2); break;
        }
        #pragma unroll
        for (int y = 0; y < 3; ++y) emit_s4(a2[y], oc, y, swv, sbv, s4p, nb, sl);
    } else {                                 // y2 = 3,4; rows 6..13
        float a2[2][2][10];
        #pragma unroll
        for (int y = 0; y < 2; ++y)
            #pragma unroll
            for (int u = 0; u < 2; ++u)
                #pragma unroll
                for (int ox = 0; ox < 10; ++ox) a2[y][u][ox] = bbv;
        switch (nic) {
            case 3:  c3_half<3, 3, 2, 6, 28>(s2c, wpk, icl, oc, nb, sl, a2); break;
            case 4:  c3_half<4, 3, 2, 6, 28>(s2c, wpk, icl, oc, nb, sl, a2); break;
            default: c3_half<6, 3, 2, 6, 28>(s2c, wpk, icl, oc, nb, sl, a2); break;
        }
        #pragma unroll
        for (int y = 0; y < 2; ++y) emit_s4(a2[y], oc, 3 + y, swv, sbv, s4p, nb, sl);
    }
}

// ---------------- C5: 120-ch GEMV over 120 s4 cells, grid (nb/256, 12) ------
__global__ __launch_bounds__(256) void k_c5(
    const u32* __restrict__ s4p, const u32* __restrict__ wpk,
    const float* __restrict__ b5, u32* __restrict__ h5p, int nb)
{
    const int sl = blockIdx.x * 256 + threadIdx.x;
    const int chg = blockIdx.y;              // channels chg*10 .. chg*10+9
    const uint2* sb = (const uint2*)s4p + sl;
    const u32* wp = wpk + WPK_W5 + chg * 2400;
    float acc[10];
    #pragma unroll
    for (int c = 0; c < 10; ++c) acc[c] = b5[chg * 10 + c];
    #pragma unroll 4
    for (int i = 0; i < 120; ++i) {          // cell i = features 2i, 2i+1
        const uint2 v = sb[(size_t)i * nb];
        #pragma unroll
        for (int c = 0; c < 10; ++c) {
            const u32* w = wp + c * 240 + 2 * i;     // uniform -> s_load
            acc[c] = dot2(v.y, w[1], dot2(v.x, w[0], acc[c]));
        }
    }
    #pragma unroll
    for (int j = 0; j < 5; ++j) {
        const int k = chg * 5 + j;
        h5p[((size_t)(k >> 1) * nb + sl) * 2 + (k & 1)] =
            packh2(tact(acc[2 * j]), tact(acc[2 * j + 1]));
    }
}

// ---------------- F6: 84-out GEMV over 30 h5 cells, grid (nb/256, 6) --------
__global__ __launch_bounds__(256) void k_f6(
    const u32* __restrict__ h5p, const u32* __restrict__ wpk,
    const float* __restrict__ f6b, u32* __restrict__ h6p, int nb)
{
    const int sl = blockIdx.x * 256 + threadIdx.x;
    const int og = blockIdx.y;               // outputs og*14 .. og*14+13
    const uint2* hb = (const uint2*)h5p + sl;
    const u32* wp = wpk + WPK_F6 + og * 14 * 60;
    float acc[14];
    #pragma unroll
    for (int o = 0; o < 14; ++o) acc[o] = f6b[og * 14 + o];
    #pragma unroll
    for (int i = 0; i < 30; ++i) {           // cell i = pair-features 2i, 2i+1
        const uint2 v = hb[(size_t)i * nb];
        #pragma unroll
        for (int o = 0; o < 14; ++o) {
            const u32* w = wp + o * 60 + 2 * i;      // uniform -> s_load
            acc[o] = dot2(v.y, w[1], dot2(v.x, w[0], acc[o]));
        }
    }
    #pragma unroll
    for (int j = 0; j < 7; ++j) {
        const int k = og * 7 + j;
        h6p[((size_t)(k >> 1) * nb + sl) * 2 + (k & 1)] =
            packh2(tact(acc[2 * j]), tact(acc[2 * j + 1]));
    }
}

// ---------------- RBF head, grid (nb/256, 5): 2 classes per block -----------
__global__ __launch_bounds__(256) void k_rbf(
    const u32* __restrict__ h6p, const float* __restrict__ rbf,
    float* __restrict__ out, int nb)
{
    const int sl = blockIdx.x * 256 + threadIdx.x;
    const int gy = blockIdx.y;
    const uint2* hb = (const uint2*)h6p + sl;
    float hv[84];
    #pragma unroll
    for (int i = 0; i < 21; ++i) {
        const uint2 v = hb[(size_t)i * nb];
        hv[4 * i]     = f16lo(v.x);
        hv[4 * i + 1] = f16hi(v.x);
        hv[4 * i + 2] = f16lo(v.y);
        hv[4 * i + 3] = f16hi(v.y);
    }
    #pragma unroll
    for (int a = 0; a < 2; ++a) {
        const int c = 2 * gy + a;
        float acc = 0.0f;
        #pragma unroll 4
        for (int i = 0; i < 84; ++i) {
            float d = hv[i] - rbf[c * 84 + i];   // uniform -> s_load
            acc += d * d;
        }
        out[(size_t)sl * 10 + c] = acc;
    }
}

extern "C" void kernel_launch(void* const* d_in, const int* in_sizes, int n_in,
                              void* d_out, int out_size, void* d_ws, size_t ws_size,
                              hipStream_t stream)
{
    const float* x    = (const float*)d_in[0];
    const float* w1   = (const float*)d_in[1];
    const float* b1   = (const float*)d_in[2];
    const float* s2w  = (const float*)d_in[3];
    const float* s2b  = (const float*)d_in[4];
    const float* w3   = (const float*)d_in[5];
    const float* b3   = (const float*)d_in[6];
    const float* s4w  = (const float*)d_in[7];
    const float* s4b  = (const float*)d_in[8];
    const float* w5   = (const float*)d_in[9];
    const float* b5   = (const float*)d_in[10];
    const float* f6w  = (const float*)d_in[11];
    const float* f6b  = (const float*)d_in[12];
    const float* rbfw = (const float*)d_in[13];
    float* out = (float*)d_out;
    char* ws = (char*)d_ws;

    // Weight pack at the tail of d_out (dead until k_rbf; k_rbf never reads
    // it and rewrites every byte of out at the end of each plan/chunk order).
    u32* WPK = (u32*)((char*)d_out +
                      (((size_t)out_size - (size_t)(WPK_N * 4)) & ~(size_t)7));
    k_wpack<<<dim3((WPK_N + 255) / 256), 256, 0, stream>>>(w1, w3, w5, f6w, WPK);

    if (ws_size >= 55312384) {
        // ---- Plan A: full-batch tail (10 dispatches) ----
        u32* S2P = (u32*)(ws);                       // 38,535,168 B (cells)
        u32* XP  = (u32*)(ws + 38535168);            // 16,777,216 B (front)
        u32* S4P = (u32*)(ws + 38535168);            // 15,728,640 B (after front)
        u32* H5P = (u32*)(ws);                       //  3,932,160 B (after c3s4)
        u32* H6P = (u32*)(ws + 4194304);             //  2,752,512 B
        for (int c = 0; c < 2; ++c) {
            k_tr  <<<dim3(128, 16), 256, 0, stream>>>(x + (size_t)c * 8192 * 1024, XP);
            k_c1s2<<<dim3(32, 42), 256, 0, stream>>>(XP, WPK, b1, s2w, s2b,
                                                     S2P + (size_t)c * 16384, 16384);
        }
        k_c3s4<<<dim3(64, 32), 256, 0, stream>>>(S2P, WPK, b3, s4w, s4b, S4P, 16384);
        k_c5  <<<dim3(64, 12), 256, 0, stream>>>(S4P, WPK, b5, H5P, 16384);
        k_f6  <<<dim3(64, 6), 256, 0, stream>>>(H5P, WPK, f6b, H6P, 16384);
        k_rbf <<<dim3(64, 5), 256, 0, stream>>>(H6P, rbfw, out, 16384);
    } else {
        // ---- Plan B: 2 chunks (13 dispatches) ----
        u32* XP  = (u32*)(ws);                       // 16,777,216 B
        u32* S2P = (u32*)(ws + 16777216);            // 19,267,584 B
        u32* S4P = (u32*)(ws);                       //  7,864,320 B (XP dead)
        u32* H5P = (u32*)(ws + 7864320);             //  1,966,080 B
        u32* H6P = (u32*)(ws + 9830400);             //  1,376,256 B
        for (int c = 0; c < 2; ++c) {
            k_tr  <<<dim3(128, 16), 256, 0, stream>>>(x + (size_t)c * 8192 * 1024, XP);
            k_c1s2<<<dim3(32, 42), 256, 0, stream>>>(XP, WPK, b1, s2w, s2b, S2P, 8192);
            k_c3s4<<<dim3(32, 32), 256, 0, stream>>>(S2P, WPK, b3, s4w, s4b, S4P, 8192);
            k_c5  <<<dim3(32, 12), 256, 0, stream>>>(S4P, WPK, b5, H5P, 8192);
            k_f6  <<<dim3(32, 6), 256, 0, stream>>>(H5P, WPK, f6b, H6P, 8192);
            k_rbf <<<dim3(32, 5), 256, 0, stream>>>(H6P, rbfw, out + (size_t)c * 8192 * 10, 8192);
        }
    }
}

// Round 5
// 315.566 us; speedup vs baseline: 1.0582x; 1.0582x over previous
//
#include <hip/hip_runtime.h>
#include <cstdint>

// LeNet-5 forward, B=16384. Batch-lane design: lane = sample, wave-uniform
// control, [feature][N] SoA layouts (coalesced), f16 pair-packed storage.
// R11 = R9 (proven 322us) with c3s4 moved to the MATRIX pipe:
//   k_c3s4m: implicit GEMM via mfma_f32_16x16x32_f16.
//     M=16 oc (dense, masked weights == reference w3*C3_MASK),
//     K=180 pad 192: k = ((ic*5+kr)*3+pr)*2+h  (pair-cells),
//     N=16 samples. Two A-frag sets (aligned/shifted weight pairs) share one
//     B-frag -> even/odd output columns. Per block: 64 samples x one y2;
//     stage 6x21 uint2 S2P cells -> LDS [252 cells][65] (stride 65 kills the
//     g-group 4-way bank conflict, 65,520 B); per wave 5q x 6 ksteps x
//     {8 ds_read_b32 imm-offset + 4 MFMA}; fused tanh->S4 epilogue.
//     Output format identical to R9 s4p (u32 [240][nb]).
//   All other kernels byte-identical to R9. WPK layout: W3 regions become
//   masked [16 oc][96] aligned+shifted (kp 90..95 zero); W5/F6 shifted up.
// Plans/offsets identical to R9 (Plan A 10 dispatches / Plan B 13).

typedef unsigned int u32;

union U32H2 { u32 u; _Float16 h[2]; };
__device__ __forceinline__ float f16lo(u32 v) { U32H2 a; a.u = v; return (float)a.h[0]; }
__device__ __forceinline__ float f16hi(u32 v) { U32H2 a; a.u = v; return (float)a.h[1]; }
__device__ __forceinline__ u32 packh2(float a, float b) {
    U32H2 x; x.h[0] = (_Float16)a; x.h[1] = (_Float16)b; return x.u;
}

typedef _Float16 h2v __attribute__((ext_vector_type(2)));
typedef _Float16 half8 __attribute__((ext_vector_type(8)));
typedef float f32x4 __attribute__((ext_vector_type(4)));
union U32V2 { u32 u; h2v v; };
union AB8 { u32 u[4]; half8 h; };

#if defined(__has_builtin)
#if __has_builtin(__builtin_amdgcn_fdot2)
#define HAVE_FDOT2 1
#endif
#endif

// c += a.h0*b.h0 + a.h1*b.h1  (f16 mul, f32 accumulate) -> v_dot2_f32_f16
__device__ __forceinline__ float dot2(u32 a, u32 b, float c) {
    U32V2 x, y; x.u = a; y.u = b;
#ifdef HAVE_FDOT2
    return __builtin_amdgcn_fdot2(x.v, y.v, c, false);
#else
    return c + (float)x.v[0] * (float)y.v[0] + (float)x.v[1] * (float)y.v[1];
#endif
}

// A*tanh(S*v), S=2/3: tanh(y) = 1 - 2/(exp(2y)+1), 2y = (4/3)v
__device__ __forceinline__ float tact(float v) {
    float e = __expf(1.3333333333f * v);
    return 1.7159f * (1.0f - 2.0f * __builtin_amdgcn_rcpf(e + 1.0f));
}

// C3 connectivity bitmask per oc (bit ic) — from reference CONNECTIONS
__device__ const u32 C3_MB[16] = {
    0x07, 0x0E, 0x1C, 0x38, 0x31, 0x23, 0x0F, 0x1E,
    0x3C, 0x39, 0x33, 0x27, 0x1B, 0x36, 0x2D, 0x3F };

// Weight-pack layout (u32 indices inside WPK):
//  W1P  @0     : [6ch][5ky][3q]  pair = (w[2q], w[2q+1]|0)          (90, pad 96)
//  W1S  @96    : [6ch][5ky][3q]  pair = (0,w0)|(w1,w2)|(w3,w4)      (90, pad 96)
//  W3A  @192   : [16 oc][96 kp]  masked aligned, kp=(ic*5+kr)*3+pr,
//                                kp 90..95 = 0                      (1536)
//  W3S  @1728  : [16 oc][96 kp]  masked shifted                     (1536)
//  W5P  @3264  : [120c][80g][3q] pair = (w5[c][g*5+2q], +1|0)       (28800)
//  F6P  @32064 : [84o][60i]      pair = (f6w[o][2i], f6w[o][2i+1])  (5040)
#define WPK_W1  0
#define WPK_W1S 96
#define WPK_W3A 192
#define WPK_W3S 1728
#define WPK_W5  3264
#define WPK_F6  32064
#define WPK_N   37104

__global__ __launch_bounds__(256) void k_wpack(
    const float* __restrict__ w1, const float* __restrict__ w3,
    const float* __restrict__ w5, const float* __restrict__ f6w,
    u32* __restrict__ wpk)
{
    const int idx = blockIdx.x * 256 + threadIdx.x;
    if (idx >= WPK_N) return;
    float a = 0.0f, b = 0.0f;
    if (idx < 192) {                         // w1 aligned / shifted
        const int s = idx >= 96;
        const int t = idx - s * 96;
        if (t < 90) {
            int ch = t / 15, r = t % 15, ky = r / 3, q = r % 3;
            const float* w = w1 + ch * 25 + ky * 5;
            if (!s) { a = w[2 * q]; if (q < 2) b = w[2 * q + 1]; }
            else if (q == 0) { b = w[0]; }
            else { a = w[2 * q - 1]; b = w[2 * q]; }
        }
    } else if (idx < WPK_W5) {               // w3 masked aligned / shifted [oc][96]
        const int t2 = idx - WPK_W3A;
        const int s = t2 >= 1536;
        const int t = t2 - s * 1536;
        const int oc = t / 96, kp = t % 96;
        if (kp < 90) {
            int ic = kp / 15, rem = kp % 15, ky = rem / 3, q = rem % 3;
            if ((C3_MB[oc] >> ic) & 1) {
                const float* w = w3 + (oc * 6 + ic) * 25 + ky * 5;
                if (!s) { a = w[2 * q]; if (q < 2) b = w[2 * q + 1]; }
                else if (q == 0) { b = w[0]; }
                else { a = w[2 * q - 1]; b = w[2 * q]; }
            }
        }
    } else if (idx < WPK_F6) {
        int t = idx - WPK_W5;
        int c = t / 240, r = t % 240, g = r / 3, q = r % 3;
        a = w5[c * 400 + g * 5 + 2 * q];
        if (q < 2) b = w5[c * 400 + g * 5 + 2 * q + 1];
    } else {
        int t = idx - WPK_F6;
        int o = t / 60, i = t % 60;
        a = f6w[o * 120 + 2 * i];
        b = f6w[o * 120 + 2 * i + 1];
    }
    wpk[idx] = packh2(a, b);
}

// ---------------- transpose: x chunk (8192,1024) f32 -> xp u32[512][8192] ---
__global__ __launch_bounds__(256) void k_tr(const float* __restrict__ x,
                                            u32* __restrict__ xp)
{
    __shared__ _Float16 lds[64 * 66];
    const int t = threadIdx.x;
    const int tb = blockIdx.x * 64;          // sample tile
    const int tp = blockIdx.y * 64;          // position tile
    #pragma unroll
    for (int i = 0; i < 16; ++i) {           // coalesced read along positions
        int idx = i * 256 + t;
        int bl = idx >> 6, pl = idx & 63;
        lds[pl * 66 + bl] = (_Float16)x[(size_t)(tb + bl) * 1024 + tp + pl];
    }
    __syncthreads();
    #pragma unroll
    for (int j = 0; j < 8; ++j) {            // coalesced pair-write along batch
        int idx = j * 256 + t;
        int pp = idx >> 6, bl = idx & 63;    // pp in [0,32)
        U32H2 u;
        u.h[0] = lds[(2 * pp) * 66 + bl];
        u.h[1] = lds[(2 * pp + 1) * 66 + bl];
        xp[(size_t)(blockIdx.y * 32 + pp) * 8192 + tb + bl] = u.u;
    }
}

// ---------------- C1 + S2 fused, grid (32, 42) — R9 exact -------------------
__global__ __launch_bounds__(256) void k_c1s2(
    const u32* __restrict__ xp, const u32* __restrict__ wpk,
    const float* __restrict__ b1,
    const float* __restrict__ s2w, const float* __restrict__ s2b,
    u32* __restrict__ s2p, int ostr)
{
    const int sl = blockIdx.x * 256 + threadIdx.x;
    const int oy2 = blockIdx.y / 3;
    const int cp  = blockIdx.y % 3;          // channels 2cp, 2cp+1
    const int y0 = 2 * oy2;
    const u32* xb = xp + sl;

    u32 wl[2][15], wls[2][15];               // aligned + shifted pairs (uniform)
    #pragma unroll
    for (int a = 0; a < 2; ++a) {
        #pragma unroll
        for (int i = 0; i < 15; ++i) wl[a][i]  = wpk[WPK_W1  + (2 * cp + a) * 15 + i];
        #pragma unroll
        for (int i = 0; i < 15; ++i) wls[a][i] = wpk[WPK_W1S + (2 * cp + a) * 15 + i];
    }

    u32 cur[6][4];                           // aligned pairs, window cols 4qx..4qx+7
    #pragma unroll
    for (int r = 0; r < 6; ++r)
        #pragma unroll
        for (int c = 0; c < 4; ++c)
            cur[r][c] = xb[(size_t)((y0 + r) * 16 + c) * 8192];

    float va[2][7], vb[2][7];                // s2 row cols 0..6 / 7..13 per ch

    #pragma unroll
    for (int qx = 0; qx < 7; ++qx) {
        float o[2][2][4];
        #pragma unroll
        for (int a = 0; a < 2; ++a) {
            const float bbv = b1[2 * cp + a];
            #pragma unroll
            for (int u = 0; u < 2; ++u)
                #pragma unroll
                for (int d = 0; d < 4; ++d) o[a][u][d] = bbv;
        }
        #pragma unroll
        for (int r = 0; r < 6; ++r) {
            #pragma unroll
            for (int u = 0; u < 2; ++u) {
                const int ky = r - u;
                if (ky < 0 || ky > 4) continue;
                #pragma unroll
                for (int a = 0; a < 2; ++a) {
                    const u32 w0 = wl[a][ky * 3 + 0];
                    const u32 w1 = wl[a][ky * 3 + 1];
                    const u32 w2 = wl[a][ky * 3 + 2];
                    const u32 v0 = wls[a][ky * 3 + 0];
                    const u32 v1 = wls[a][ky * 3 + 1];
                    const u32 v2 = wls[a][ky * 3 + 2];
                    o[a][u][0] = dot2(cur[r][0], w0, dot2(cur[r][1], w1, dot2(cur[r][2], w2, o[a][u][0])));
                    o[a][u][1] = dot2(cur[r][0], v0, dot2(cur[r][1], v1, dot2(cur[r][2], v2, o[a][u][1])));
                    o[a][u][2] = dot2(cur[r][1], w0, dot2(cur[r][2], w1, dot2(cur[r][3], w2, o[a][u][2])));
                    o[a][u][3] = dot2(cur[r][1], v0, dot2(cur[r][2], v1, dot2(cur[r][3], v2, o[a][u][3])));
                }
            }
        }
        #pragma unroll
        for (int a = 0; a < 2; ++a) {
            const int ch = 2 * cp + a;
            const float sw = s2w[ch], sb = s2b[ch];
            float m0 = 0.25f * (tact(o[a][0][0]) + tact(o[a][0][1]) + tact(o[a][0][2]) + tact(o[a][0][3]));
            float m1 = 0.25f * (tact(o[a][1][0]) + tact(o[a][1][1]) + tact(o[a][1][2]) + tact(o[a][1][3]));
            va[a][qx] = tact(sw * m0 + sb);
            vb[a][qx] = tact(sw * m1 + sb);
        }
        if (qx < 6) {                        // slide window: +2 new pairs/row
            #pragma unroll
            for (int r = 0; r < 6; ++r) {
                cur[r][0] = cur[r][2];
                cur[r][1] = cur[r][3];
                cur[r][2] = xb[(size_t)((y0 + r) * 16 + 2 * qx + 4) * 8192];
                cur[r][3] = xb[(size_t)((y0 + r) * 16 + 2 * qx + 5) * 8192];
            }
        }
    }
    // repack to adjacent-column pairs and store into [fh][ostr][2] cells
    #pragma unroll
    for (int a = 0; a < 2; ++a) {
        u32 o7[7];
        o7[0] = packh2(va[a][0], va[a][1]);
        o7[1] = packh2(va[a][2], va[a][3]);
        o7[2] = packh2(va[a][4], va[a][5]);
        o7[3] = packh2(va[a][6], vb[a][0]);
        o7[4] = packh2(vb[a][1], vb[a][2]);
        o7[5] = packh2(vb[a][3], vb[a][4]);
        o7[6] = packh2(vb[a][5], vb[a][6]);
        const int ch = 2 * cp + a;
        const int f0 = ch * 98 + oy2 * 7;    // parity = oy2&1 (uniform)
        const int fh0 = f0 >> 1;
        uint2* p2 = (uint2*)s2p;
        uint2 t;
        if ((oy2 & 1) == 0) {
            t.x = o7[0]; t.y = o7[1]; p2[(size_t)(fh0 + 0) * ostr + sl] = t;
            t.x = o7[2]; t.y = o7[3]; p2[(size_t)(fh0 + 1) * ostr + sl] = t;
            t.x = o7[4]; t.y = o7[5]; p2[(size_t)(fh0 + 2) * ostr + sl] = t;
            s2p[((size_t)(fh0 + 3) * ostr + sl) * 2] = o7[6];
        } else {
            s2p[((size_t)fh0 * ostr + sl) * 2 + 1] = o7[0];
            t.x = o7[1]; t.y = o7[2]; p2[(size_t)(fh0 + 1) * ostr + sl] = t;
            t.x = o7[3]; t.y = o7[4]; p2[(size_t)(fh0 + 2) * ostr + sl] = t;
            t.x = o7[5]; t.y = o7[6]; p2[(size_t)(fh0 + 3) * ostr + sl] = t;
        }
    }
}

// ---------------- C3 + S4 fused via MFMA, grid (nb/64, 5) -------------------
// Block = 64 samples x one y2. M=16 oc, N=16 samples per wave, K=192.
// k = ((ic*5+kr)*3+pr)*2 + h; A row = lane&15 (oc), B col = lane&15 (sample),
// lane k-group g = lane>>4 covers k 32s+8g..+7 per step s (pairs kp=16s+4g+m).
// LDS cell(ic,lr,pr) = ic*42 + lr*7 + pr, lr = row-2y2 in 0..5; stride 65.
__global__ __launch_bounds__(256) void k_c3s4m(
    const u32* __restrict__ s2p, const u32* __restrict__ wpk,
    const float* __restrict__ b3, const float* __restrict__ s4w,
    const float* __restrict__ s4b, u32* __restrict__ s4p, int nb)
{
    __shared__ u32 lds[252 * 65];            // 65,520 B
    const int t = threadIdx.x;
    const int y2 = blockIdx.y;
    const int base = blockIdx.x * 64;        // sample base
    const uint2* s2c = (const uint2*)s2p;

    // ---- stage: 6 ic x 21 uint2 cells x 64 samples (coalesced) ----
    for (int i = 0; i < 32; ++i) {
        int idx = i * 256 + t;
        if (idx < 8064) {
            int ic = idx / 1344;             // 21*64
            int r = idx - ic * 1344;
            int cell = r >> 6, sLoc = r & 63;
            uint2 v = s2c[(size_t)(49 * ic + 7 * y2 + cell) * nb + base + sLoc];
            lds[(ic * 42 + 2 * cell) * 65 + sLoc]     = v.x;
            lds[(ic * 42 + 2 * cell + 1) * 65 + sLoc] = v.y;
        }
    }

    // ---- per-lane setup ----
    const int l = t & 63, w = t >> 6;
    const int g = l >> 4, col = l & 15;
    const int sLocal = w * 16 + col;         // this lane's sample (B/C col)
    const int ocA = col;                     // A row supplied by this lane

    AB8 wA[6], wS[6];                        // A frags: aligned / shifted
    #pragma unroll
    for (int s = 0; s < 6; ++s)
        #pragma unroll
        for (int m = 0; m < 4; ++m) {
            int kp = 16 * s + 4 * g + m;
            wA[s].u[m] = wpk[WPK_W3A + ocA * 96 + kp];
            wS[s].u[m] = wpk[WPK_W3S + ocA * 96 + kp];
        }

    int vbase[6][4];                         // LDS base index per (s,m) slot
    u32 zmask[4];                            // pad-zero masks (s=5 only)
    #pragma unroll
    for (int s = 0; s < 6; ++s)
        #pragma unroll
        for (int m = 0; m < 4; ++m) {
            int kp = 16 * s + 4 * g + m;
            int ic = kp / 15;
            int rem = kp - ic * 15;
            int kr = rem / 3;
            int pr = rem - kr * 3;
            int c = ic * 42 + kr * 7 + pr;
            if (kp >= 90) c = 240;           // clamp (value discarded via mask)
            vbase[s][m] = c * 65 + sLocal;
            if (s == 5) zmask[m] = (kp < 90) ? 0xFFFFFFFFu : 0u;
        }

    float b3v[4], swv[4], sbv[4];            // epilogue params for oc = 4g+r
    #pragma unroll
    for (int r = 0; r < 4; ++r) {
        b3v[r] = b3[4 * g + r];
        swv[r] = s4w[4 * g + r];
        sbv[r] = s4b[4 * g + r];
    }

    __syncthreads();

    float pool[4][5];
    #pragma unroll
    for (int r = 0; r < 4; ++r)
        #pragma unroll
        for (int x2 = 0; x2 < 5; ++x2) pool[r][x2] = 0.0f;

    #pragma unroll
    for (int q = 0; q < 5; ++q) {
        f32x4 a00 = {0.f, 0.f, 0.f, 0.f};    // u=0 (row 2y2),   ox=2q
        f32x4 a01 = {0.f, 0.f, 0.f, 0.f};    // u=0,             ox=2q+1
        f32x4 a10 = {0.f, 0.f, 0.f, 0.f};    // u=1 (row 2y2+1), ox=2q
        f32x4 a11 = {0.f, 0.f, 0.f, 0.f};    // u=1,             ox=2q+1
        #pragma unroll
        for (int s = 0; s < 6; ++s) {
            AB8 b0, b1;
            #pragma unroll
            for (int m = 0; m < 4; ++m) {
                u32 x0 = lds[vbase[s][m] + q * 65];        // u=0: +q cells
                u32 x1 = lds[vbase[s][m] + (q + 7) * 65];  // u=1: +7+q cells
                if (s == 5) { x0 &= zmask[m]; x1 &= zmask[m]; }
                b0.u[m] = x0; b1.u[m] = x1;
            }
            a00 = __builtin_amdgcn_mfma_f32_16x16x32_f16(wA[s].h, b0.h, a00, 0, 0, 0);
            a01 = __builtin_amdgcn_mfma_f32_16x16x32_f16(wS[s].h, b0.h, a01, 0, 0, 0);
            a10 = __builtin_amdgcn_mfma_f32_16x16x32_f16(wA[s].h, b1.h, a10, 0, 0, 0);
            a11 = __builtin_amdgcn_mfma_f32_16x16x32_f16(wS[s].h, b1.h, a11, 0, 0, 0);
        }
        // fused tanh + S4 reshape-flat pooling (flat f = u*10 + ox, x2 = f>>2)
        #pragma unroll
        for (int r = 0; r < 4; ++r) {
            pool[r][(2 * q) >> 2]      += tact(a00[r] + b3v[r]);
            pool[r][(2 * q + 1) >> 2]  += tact(a01[r] + b3v[r]);
            pool[r][(10 + 2 * q) >> 2] += tact(a10[r] + b3v[r]);
            pool[r][(11 + 2 * q) >> 2] += tact(a11[r] + b3v[r]);
        }
    }

    // S4 affine + tanh, store in R9 s4p format: u32[(oc*5+y2)*3+j][nb]
    const int sG = base + sLocal;
    #pragma unroll
    for (int r = 0; r < 4; ++r) {
        float so[5];
        #pragma unroll
        for (int x2 = 0; x2 < 5; ++x2)
            so[x2] = tact(0.25f * pool[r][x2] * swv[r] + sbv[r]);
        const int ocr = 4 * g + r;
        const size_t gf = (size_t)(ocr * 5 + y2) * 3;
        s4p[(gf + 0) * nb + sG] = packh2(so[0], so[1]);
        s4p[(gf + 1) * nb + sG] = packh2(so[2], so[3]);
        s4p[(gf + 2) * nb + sG] = packh2(so[4], 0.0f);
    }
}

// ---------------- C5: 120-ch GEMV over 240 s4 pairs, grid (nb/256, 12) ------
__global__ __launch_bounds__(256) void k_c5(
    const u32* __restrict__ s4p, const u32* __restrict__ wpk,
    const float* __restrict__ b5, u32* __restrict__ h5p, int nb)
{
    const int sl = blockIdx.x * 256 + threadIdx.x;
    const int chg = blockIdx.y;              // channels chg*10 .. chg*10+9
    const u32* wp = wpk + WPK_W5 + chg * 10 * 240;
    float acc[10];
    #pragma unroll
    for (int c = 0; c < 10; ++c) acc[c] = b5[chg * 10 + c];
    #pragma unroll 4
    for (int i = 0; i < 240; ++i) {
        const u32 v = s4p[(size_t)i * nb + sl];
        #pragma unroll
        for (int c = 0; c < 10; ++c)
            acc[c] = dot2(v, wp[c * 240 + i], acc[c]);   // uniform -> s_load
    }
    #pragma unroll
    for (int j = 0; j < 5; ++j)
        h5p[(size_t)(chg * 5 + j) * nb + sl] =
            packh2(tact(acc[2 * j]), tact(acc[2 * j + 1]));
}

// ---------------- F6: 84-out GEMV over 60 h5 pairs, grid (nb/256, 6) --------
__global__ __launch_bounds__(256) void k_f6(
    const u32* __restrict__ h5p, const u32* __restrict__ wpk,
    const float* __restrict__ f6b, u32* __restrict__ h6p, int nb)
{
    const int sl = blockIdx.x * 256 + threadIdx.x;
    const int og = blockIdx.y;               // outputs og*14 .. og*14+13
    const u32* wp = wpk + WPK_F6 + og * 14 * 60;
    float acc[14];
    #pragma unroll
    for (int o = 0; o < 14; ++o) acc[o] = f6b[og * 14 + o];
    #pragma unroll 4
    for (int i = 0; i < 60; ++i) {
        const u32 v = h5p[(size_t)i * nb + sl];
        #pragma unroll
        for (int o = 0; o < 14; ++o)
            acc[o] = dot2(v, wp[o * 60 + i], acc[o]);    // uniform -> s_load
    }
    #pragma unroll
    for (int j = 0; j < 7; ++j)
        h6p[(size_t)(og * 7 + j) * nb + sl] =
            packh2(tact(acc[2 * j]), tact(acc[2 * j + 1]));
}

// ---------------- RBF head, grid (nb/256, 5): 2 classes per block -----------
__global__ __launch_bounds__(256) void k_rbf(
    const u32* __restrict__ h6p, const float* __restrict__ rbf,
    float* __restrict__ out, int nb)
{
    const int sl = blockIdx.x * 256 + threadIdx.x;
    const int gy = blockIdx.y;
    float hv[84];
    #pragma unroll
    for (int i = 0; i < 42; ++i) {
        const u32 v = h6p[(size_t)i * nb + sl];
        hv[2 * i]     = f16lo(v);
        hv[2 * i + 1] = f16hi(v);
    }
    #pragma unroll
    for (int a = 0; a < 2; ++a) {
        const int c = 2 * gy + a;
        float acc = 0.0f;
        #pragma unroll 4
        for (int i = 0; i < 84; ++i) {
            float d = hv[i] - rbf[c * 84 + i];   // uniform -> s_load
            acc += d * d;
        }
        out[(size_t)sl * 10 + c] = acc;
    }
}

extern "C" void kernel_launch(void* const* d_in, const int* in_sizes, int n_in,
                              void* d_out, int out_size, void* d_ws, size_t ws_size,
                              hipStream_t stream)
{
    const float* x    = (const float*)d_in[0];
    const float* w1   = (const float*)d_in[1];
    const float* b1   = (const float*)d_in[2];
    const float* s2w  = (const float*)d_in[3];
    const float* s2b  = (const float*)d_in[4];
    const float* w3   = (const float*)d_in[5];
    const float* b3   = (const float*)d_in[6];
    const float* s4w  = (const float*)d_in[7];
    const float* s4b  = (const float*)d_in[8];
    const float* w5   = (const float*)d_in[9];
    const float* b5   = (const float*)d_in[10];
    const float* f6w  = (const float*)d_in[11];
    const float* f6b  = (const float*)d_in[12];
    const float* rbfw = (const float*)d_in[13];
    float* out = (float*)d_out;
    char* ws = (char*)d_ws;

    // Weight pack at the tail of d_out (dead until k_rbf; k_rbf never reads
    // it and rewrites every byte of out at the end of each plan/chunk order).
    u32* WPK = (u32*)((char*)d_out +
                      (((size_t)out_size - (size_t)(WPK_N * 4)) & ~(size_t)7));
    k_wpack<<<dim3((WPK_N + 255) / 256), 256, 0, stream>>>(w1, w3, w5, f6w, WPK);

    if (ws_size >= 55312384) {
        // ---- Plan A: full-batch tail (10 dispatches) ----
        u32* S2P = (u32*)(ws);                       // 38,535,168 B (cells)
        u32* XP  = (u32*)(ws + 38535168);            // 16,777,216 B (front)
        u32* S4P = (u32*)(ws + 38535168);            // 15,728,640 B (after front)
        u32* H5P = (u32*)(ws);                       //  3,932,160 B (after c3s4)
        u32* H6P = (u32*)(ws + 4194304);             //  2,752,512 B
        for (int c = 0; c < 2; ++c) {
            k_tr  <<<dim3(128, 16), 256, 0, stream>>>(x + (size_t)c * 8192 * 1024, XP);
            k_c1s2<<<dim3(32, 42), 256, 0, stream>>>(XP, WPK, b1, s2w, s2b,
                                                     S2P + (size_t)c * 16384, 16384);
        }
        k_c3s4m<<<dim3(256, 5), 256, 0, stream>>>(S2P, WPK, b3, s4w, s4b, S4P, 16384);
        k_c5  <<<dim3(64, 12), 256, 0, stream>>>(S4P, WPK, b5, H5P, 16384);
        k_f6  <<<dim3(64, 6), 256, 0, stream>>>(H5P, WPK, f6b, H6P, 16384);
        k_rbf <<<dim3(64, 5), 256, 0, stream>>>(H6P, rbfw, out, 16384);
    } else {
        // ---- Plan B: 2 chunks (13 dispatches) ----
        u32* XP  = (u32*)(ws);                       // 16,777,216 B
        u32* S2P = (u32*)(ws + 16777216);            // 19,267,584 B
        u32* S4P = (u32*)(ws);                       //  7,864,320 B (XP dead)
        u32* H5P = (u32*)(ws + 7864320);             //  1,966,080 B
        u32* H6P = (u32*)(ws + 9830400);             //  1,376,256 B
        for (int c = 0; c < 2; ++c) {
            k_tr  <<<dim3(128, 16), 256, 0, stream>>>(x + (size_t)c * 8192 * 1024, XP);
            k_c1s2<<<dim3(32, 42), 256, 0, stream>>>(XP, WPK, b1, s2w, s2b, S2P, 8192);
            k_c3s4m<<<dim3(128, 5), 256, 0, stream>>>(S2P, WPK, b3, s4w, s4b, S4P, 8192);
            k_c5  <<<dim3(32, 12), 256, 0, stream>>>(S4P, WPK, b5, H5P, 8192);
            k_f6  <<<dim3(32, 6), 256, 0, stream>>>(H5P, WPK, f6b, H6P, 8192);
            k_rbf <<<dim3(32, 5), 256, 0, stream>>>(H6P, rbfw, out + (size_t)c * 8192 * 10, 8192);
        }
    }
}

// Round 6
// 298.338 us; speedup vs baseline: 1.1193x; 1.0577x over previous
//
#include <hip/hip_runtime.h>
#include <cstdint>

// LeNet-5 forward, B=16384. Batch-lane design: lane = sample, wave-uniform
// control, [feature][N] SoA layouts (coalesced), f16 pair-packed storage.
// R12 = R11 (proven 315us, c3s4 on MFMA) + C1S2 moved to the MATRIX pipe:
//   k_c1s2m: implicit GEMM via mfma_f32_16x16x32_f16, ONE k-step per MFMA.
//     M=16 rows = 2*oc+par (6 oc x aligned/shifted parity; rows 12-15 zero),
//     K=32 (pad of 30 = 5ky x 3pr x 2h), N=16 samples/wave.
//     Block = 64 samples x one oy2: stage XP rows y0*16..+95 -> LDS
//     [126 cells][65] (cells 96..125 zeroed for kp=15 pad reads; 32,760 B,
//     4 blocks/CU). Per wave: 7q x 2u x 2d MFMAs; cols 4q..4q+3 = (d,par)
//     all in-lane -> pool+tanh epilogue per lane; S2P output byte-identical
//     to R9/R11 (uint2 [fh][ostr][2] cells).
//   c3s4m / c5 / f6 / rbf / k_tr / k_wpack byte-identical to R11.
// Plans/offsets identical to R11 (Plan A 10 dispatches / Plan B 13).

typedef unsigned int u32;

union U32H2 { u32 u; _Float16 h[2]; };
__device__ __forceinline__ float f16lo(u32 v) { U32H2 a; a.u = v; return (float)a.h[0]; }
__device__ __forceinline__ float f16hi(u32 v) { U32H2 a; a.u = v; return (float)a.h[1]; }
__device__ __forceinline__ u32 packh2(float a, float b) {
    U32H2 x; x.h[0] = (_Float16)a; x.h[1] = (_Float16)b; return x.u;
}

typedef _Float16 h2v __attribute__((ext_vector_type(2)));
typedef _Float16 half8 __attribute__((ext_vector_type(8)));
typedef float f32x4 __attribute__((ext_vector_type(4)));
union U32V2 { u32 u; h2v v; };
union AB8 { u32 u[4]; half8 h; };

#if defined(__has_builtin)
#if __has_builtin(__builtin_amdgcn_fdot2)
#define HAVE_FDOT2 1
#endif
#endif

// c += a.h0*b.h0 + a.h1*b.h1  (f16 mul, f32 accumulate) -> v_dot2_f32_f16
__device__ __forceinline__ float dot2(u32 a, u32 b, float c) {
    U32V2 x, y; x.u = a; y.u = b;
#ifdef HAVE_FDOT2
    return __builtin_amdgcn_fdot2(x.v, y.v, c, false);
#else
    return c + (float)x.v[0] * (float)y.v[0] + (float)x.v[1] * (float)y.v[1];
#endif
}

// A*tanh(S*v), S=2/3: tanh(y) = 1 - 2/(exp(2y)+1), 2y = (4/3)v
__device__ __forceinline__ float tact(float v) {
    float e = __expf(1.3333333333f * v);
    return 1.7159f * (1.0f - 2.0f * __builtin_amdgcn_rcpf(e + 1.0f));
}

// C3 connectivity bitmask per oc (bit ic) — from reference CONNECTIONS
__device__ const u32 C3_MB[16] = {
    0x07, 0x0E, 0x1C, 0x38, 0x31, 0x23, 0x0F, 0x1E,
    0x3C, 0x39, 0x33, 0x27, 0x1B, 0x36, 0x2D, 0x3F };

// Weight-pack layout (u32 indices inside WPK):
//  W1P  @0     : [6ch][5ky][3q]  pair = (w[2q], w[2q+1]|0)          (90, pad 96)
//  W1S  @96    : [6ch][5ky][3q]  pair = (0,w0)|(w1,w2)|(w3,w4)      (90, pad 96)
//  W3A  @192   : [16 oc][96 kp]  masked aligned, kp=(ic*5+kr)*3+pr,
//                                kp 90..95 = 0                      (1536)
//  W3S  @1728  : [16 oc][96 kp]  masked shifted                     (1536)
//  W5P  @3264  : [120c][80g][3q] pair = (w5[c][g*5+2q], +1|0)       (28800)
//  F6P  @32064 : [84o][60i]      pair = (f6w[o][2i], f6w[o][2i+1])  (5040)
#define WPK_W1  0
#define WPK_W1S 96
#define WPK_W3A 192
#define WPK_W3S 1728
#define WPK_W5  3264
#define WPK_F6  32064
#define WPK_N   37104

__global__ __launch_bounds__(256) void k_wpack(
    const float* __restrict__ w1, const float* __restrict__ w3,
    const float* __restrict__ w5, const float* __restrict__ f6w,
    u32* __restrict__ wpk)
{
    const int idx = blockIdx.x * 256 + threadIdx.x;
    if (idx >= WPK_N) return;
    float a = 0.0f, b = 0.0f;
    if (idx < 192) {                         // w1 aligned / shifted
        const int s = idx >= 96;
        const int t = idx - s * 96;
        if (t < 90) {
            int ch = t / 15, r = t % 15, ky = r / 3, q = r % 3;
            const float* w = w1 + ch * 25 + ky * 5;
            if (!s) { a = w[2 * q]; if (q < 2) b = w[2 * q + 1]; }
            else if (q == 0) { b = w[0]; }
            else { a = w[2 * q - 1]; b = w[2 * q]; }
        }
    } else if (idx < WPK_W5) {               // w3 masked aligned / shifted [oc][96]
        const int t2 = idx - WPK_W3A;
        const int s = t2 >= 1536;
        const int t = t2 - s * 1536;
        const int oc = t / 96, kp = t % 96;
        if (kp < 90) {
            int ic = kp / 15, rem = kp % 15, ky = rem / 3, q = rem % 3;
            if ((C3_MB[oc] >> ic) & 1) {
                const float* w = w3 + (oc * 6 + ic) * 25 + ky * 5;
                if (!s) { a = w[2 * q]; if (q < 2) b = w[2 * q + 1]; }
                else if (q == 0) { b = w[0]; }
                else { a = w[2 * q - 1]; b = w[2 * q]; }
            }
        }
    } else if (idx < WPK_F6) {
        int t = idx - WPK_W5;
        int c = t / 240, r = t % 240, g = r / 3, q = r % 3;
        a = w5[c * 400 + g * 5 + 2 * q];
        if (q < 2) b = w5[c * 400 + g * 5 + 2 * q + 1];
    } else {
        int t = idx - WPK_F6;
        int o = t / 60, i = t % 60;
        a = f6w[o * 120 + 2 * i];
        b = f6w[o * 120 + 2 * i + 1];
    }
    wpk[idx] = packh2(a, b);
}

// ---------------- transpose: x chunk (8192,1024) f32 -> xp u32[512][8192] ---
__global__ __launch_bounds__(256) void k_tr(const float* __restrict__ x,
                                            u32* __restrict__ xp)
{
    __shared__ _Float16 lds[64 * 66];
    const int t = threadIdx.x;
    const int tb = blockIdx.x * 64;          // sample tile
    const int tp = blockIdx.y * 64;          // position tile
    #pragma unroll
    for (int i = 0; i < 16; ++i) {           // coalesced read along positions
        int idx = i * 256 + t;
        int bl = idx >> 6, pl = idx & 63;
        lds[pl * 66 + bl] = (_Float16)x[(size_t)(tb + bl) * 1024 + tp + pl];
    }
    __syncthreads();
    #pragma unroll
    for (int j = 0; j < 8; ++j) {            // coalesced pair-write along batch
        int idx = j * 256 + t;
        int pp = idx >> 6, bl = idx & 63;    // pp in [0,32)
        U32H2 u;
        u.h[0] = lds[(2 * pp) * 66 + bl];
        u.h[1] = lds[(2 * pp + 1) * 66 + bl];
        xp[(size_t)(blockIdx.y * 32 + pp) * 8192 + tb + bl] = u.u;
    }
}

// ---------------- C1 + S2 fused via MFMA, grid (nb/64, 14) ------------------
// Block = 64 samples x one oy2. M rows rho = 2*oc+par (12 used), K = 32
// (kp = ky*3+pr, halves; kp 15 = pad -> zeroed LDS cells), N = 16/wave.
// B cell for kp at (u,q,d) = [ky*16+pr] + u*16 + 2q+d; per (q,u): d=0 MFMA
// gives conv cols (4q par0, 4q+1 par1), d=1 gives (4q+2, 4q+3) -> the 2x2
// pool cols land in ONE lane's regs (r = 2*(oc-2g)+par).
__global__ __launch_bounds__(256) void k_c1s2m(
    const u32* __restrict__ xp, const u32* __restrict__ wpk,
    const float* __restrict__ b1,
    const float* __restrict__ s2w, const float* __restrict__ s2b,
    u32* __restrict__ s2p, int nxp, int ostr)
{
    __shared__ u32 lds[126 * 65];            // 32,760 B; cells 96..125 zero
    const int t = threadIdx.x;
    const int oy2 = blockIdx.y;
    const int base = blockIdx.x * 64;
    const int y0 = 2 * oy2;

    // zero pad cells 96..125
    for (int i = t; i < 30 * 65; i += 256) lds[96 * 65 + i] = 0;
    // stage XP rows y0*16 .. y0*16+95 x 64 samples (uint2 coalesced)
    {
        const uint2* xp2 = (const uint2*)xp;
        const int nxp2 = nxp >> 1;
        #pragma unroll
        for (int i = 0; i < 12; ++i) {
            int idx = i * 256 + t;           // 96 cells x 32 sample-pairs
            int cell = idx >> 5, sp = idx & 31;
            uint2 v = xp2[(size_t)(y0 * 16 + cell) * nxp2 + (base >> 1) + sp];
            lds[cell * 65 + 2 * sp]     = v.x;
            lds[cell * 65 + 2 * sp + 1] = v.y;
        }
    }

    const int l = t & 63, w = t >> 6;
    const int g = l >> 4, col = l & 15;
    const int sLocal = w * 16 + col;         // this lane's sample (B/C col)
    const int rho = col;                     // A row this lane supplies
    const int ocw = rho >> 1, parw = rho & 1;

    AB8 wA;                                  // A frag: 4 u32 (one k-step)
    #pragma unroll
    for (int m = 0; m < 4; ++m) {
        int kp = 4 * g + m;
        u32 v = 0;
        if (rho < 12 && kp < 15)
            v = wpk[(parw ? WPK_W1S : WPK_W1) + ocw * 15 + kp];
        wA.u[m] = v;
    }

    int voff[4];                             // LDS base per m (u=q=d=0)
    #pragma unroll
    for (int m = 0; m < 4; ++m) {
        int kp = 4 * g + m;
        int c = (kp < 15) ? ((kp / 3) * 16 + kp % 3) : 96;
        voff[m] = c * 65 + sLocal;
    }

    // epilogue params: lane's 4 acc rows = 4g..4g+3 -> ocs 2g, 2g+1
    const int oc0 = 2 * g;
    float b1v0 = 0.f, b1v1 = 0.f, sw0 = 0.f, sb0 = 0.f, sw1 = 0.f, sb1 = 0.f;
    if (g < 3) {
        b1v0 = b1[oc0];     b1v1 = b1[oc0 + 1];
        sw0  = s2w[oc0];    sb0  = s2b[oc0];
        sw1  = s2w[oc0 + 1]; sb1 = s2b[oc0 + 1];
    }

    __syncthreads();

    float va[2][7], vb[2][7];                // per lane-oc: s2 cols 0..6 / 7..13

    #pragma unroll
    for (int q = 0; q < 7; ++q) {
        f32x4 a00 = {0.f,0.f,0.f,0.f};       // u=0, d=0: cols 4q,4q+1
        f32x4 a01 = {0.f,0.f,0.f,0.f};       // u=0, d=1: cols 4q+2,4q+3
        f32x4 a10 = {0.f,0.f,0.f,0.f};       // u=1, d=0
        f32x4 a11 = {0.f,0.f,0.f,0.f};       // u=1, d=1
        AB8 b;
        #pragma unroll
        for (int m = 0; m < 4; ++m) b.u[m] = lds[voff[m] + (2 * q) * 65];
        a00 = __builtin_amdgcn_mfma_f32_16x16x32_f16(wA.h, b.h, a00, 0, 0, 0);
        #pragma unroll
        for (int m = 0; m < 4; ++m) b.u[m] = lds[voff[m] + (2 * q + 1) * 65];
        a01 = __builtin_amdgcn_mfma_f32_16x16x32_f16(wA.h, b.h, a01, 0, 0, 0);
        #pragma unroll
        for (int m = 0; m < 4; ++m) b.u[m] = lds[voff[m] + (16 + 2 * q) * 65];
        a10 = __builtin_amdgcn_mfma_f32_16x16x32_f16(wA.h, b.h, a10, 0, 0, 0);
        #pragma unroll
        for (int m = 0; m < 4; ++m) b.u[m] = lds[voff[m] + (17 + 2 * q) * 65];
        a11 = __builtin_amdgcn_mfma_f32_16x16x32_f16(wA.h, b.h, a11, 0, 0, 0);

        // pool: acc reg r = 2*(oc-2g)+par; cols d*2+par = 4q..4q+3
        float m00 = 0.25f * (tact(a00[0] + b1v0) + tact(a00[1] + b1v0) +
                             tact(a01[0] + b1v0) + tact(a01[1] + b1v0));
        float m01 = 0.25f * (tact(a00[2] + b1v1) + tact(a00[3] + b1v1) +
                             tact(a01[2] + b1v1) + tact(a01[3] + b1v1));
        float m10 = 0.25f * (tact(a10[0] + b1v0) + tact(a10[1] + b1v0) +
                             tact(a11[0] + b1v0) + tact(a11[1] + b1v0));
        float m11 = 0.25f * (tact(a10[2] + b1v1) + tact(a10[3] + b1v1) +
                             tact(a11[2] + b1v1) + tact(a11[3] + b1v1));
        va[0][q] = tact(sw0 * m00 + sb0);
        vb[0][q] = tact(sw0 * m10 + sb0);
        va[1][q] = tact(sw1 * m01 + sb1);
        vb[1][q] = tact(sw1 * m11 + sb1);
    }

    // store (lanes g<3 own chs 2g, 2g+1): R9 o7 pack into [fh][ostr][2] cells
    if (g < 3) {
        const int sl = base + sLocal;
        #pragma unroll
        for (int a = 0; a < 2; ++a) {
            u32 o7[7];
            o7[0] = packh2(va[a][0], va[a][1]);
            o7[1] = packh2(va[a][2], va[a][3]);
            o7[2] = packh2(va[a][4], va[a][5]);
            o7[3] = packh2(va[a][6], vb[a][0]);
            o7[4] = packh2(vb[a][1], vb[a][2]);
            o7[5] = packh2(vb[a][3], vb[a][4]);
            o7[6] = packh2(vb[a][5], vb[a][6]);
            const int ch = oc0 + a;
            const int f0 = ch * 98 + oy2 * 7;
            const int fh0 = f0 >> 1;
            uint2* p2 = (uint2*)s2p;
            uint2 tt;
            if ((oy2 & 1) == 0) {
                tt.x = o7[0]; tt.y = o7[1]; p2[(size_t)(fh0 + 0) * ostr + sl] = tt;
                tt.x = o7[2]; tt.y = o7[3]; p2[(size_t)(fh0 + 1) * ostr + sl] = tt;
                tt.x = o7[4]; tt.y = o7[5]; p2[(size_t)(fh0 + 2) * ostr + sl] = tt;
                s2p[((size_t)(fh0 + 3) * ostr + sl) * 2] = o7[6];
            } else {
                s2p[((size_t)fh0 * ostr + sl) * 2 + 1] = o7[0];
                tt.x = o7[1]; tt.y = o7[2]; p2[(size_t)(fh0 + 1) * ostr + sl] = tt;
                tt.x = o7[3]; tt.y = o7[4]; p2[(size_t)(fh0 + 2) * ostr + sl] = tt;
                tt.x = o7[5]; tt.y = o7[6]; p2[(size_t)(fh0 + 3) * ostr + sl] = tt;
            }
        }
    }
}

// ---------------- C3 + S4 fused via MFMA, grid (nb/64, 5) — R11 exact -------
__global__ __launch_bounds__(256) void k_c3s4m(
    const u32* __restrict__ s2p, const u32* __restrict__ wpk,
    const float* __restrict__ b3, const float* __restrict__ s4w,
    const float* __restrict__ s4b, u32* __restrict__ s4p, int nb)
{
    __shared__ u32 lds[252 * 65];            // 65,520 B
    const int t = threadIdx.x;
    const int y2 = blockIdx.y;
    const int base = blockIdx.x * 64;        // sample base
    const uint2* s2c = (const uint2*)s2p;

    // ---- stage: 6 ic x 21 uint2 cells x 64 samples (coalesced) ----
    for (int i = 0; i < 32; ++i) {
        int idx = i * 256 + t;
        if (idx < 8064) {
            int ic = idx / 1344;             // 21*64
            int r = idx - ic * 1344;
            int cell = r >> 6, sLoc = r & 63;
            uint2 v = s2c[(size_t)(49 * ic + 7 * y2 + cell) * nb + base + sLoc];
            lds[(ic * 42 + 2 * cell) * 65 + sLoc]     = v.x;
            lds[(ic * 42 + 2 * cell + 1) * 65 + sLoc] = v.y;
        }
    }

    // ---- per-lane setup ----
    const int l = t & 63, w = t >> 6;
    const int g = l >> 4, col = l & 15;
    const int sLocal = w * 16 + col;         // this lane's sample (B/C col)
    const int ocA = col;                     // A row supplied by this lane

    AB8 wA[6], wS[6];                        // A frags: aligned / shifted
    #pragma unroll
    for (int s = 0; s < 6; ++s)
        #pragma unroll
        for (int m = 0; m < 4; ++m) {
            int kp = 16 * s + 4 * g + m;
            wA[s].u[m] = wpk[WPK_W3A + ocA * 96 + kp];
            wS[s].u[m] = wpk[WPK_W3S + ocA * 96 + kp];
        }

    int vbase[6][4];                         // LDS base index per (s,m) slot
    u32 zmask[4];                            // pad-zero masks (s=5 only)
    #pragma unroll
    for (int s = 0; s < 6; ++s)
        #pragma unroll
        for (int m = 0; m < 4; ++m) {
            int kp = 16 * s + 4 * g + m;
            int ic = kp / 15;
            int rem = kp - ic * 15;
            int kr = rem / 3;
            int pr = rem - kr * 3;
            int c = ic * 42 + kr * 7 + pr;
            if (kp >= 90) c = 240;           // clamp (value discarded via mask)
            vbase[s][m] = c * 65 + sLocal;
            if (s == 5) zmask[m] = (kp < 90) ? 0xFFFFFFFFu : 0u;
        }

    float b3v[4], swv[4], sbv[4];            // epilogue params for oc = 4g+r
    #pragma unroll
    for (int r = 0; r < 4; ++r) {
        b3v[r] = b3[4 * g + r];
        swv[r] = s4w[4 * g + r];
        sbv[r] = s4b[4 * g + r];
    }

    __syncthreads();

    float pool[4][5];
    #pragma unroll
    for (int r = 0; r < 4; ++r)
        #pragma unroll
        for (int x2 = 0; x2 < 5; ++x2) pool[r][x2] = 0.0f;

    #pragma unroll
    for (int q = 0; q < 5; ++q) {
        f32x4 a00 = {0.f, 0.f, 0.f, 0.f};    // u=0 (row 2y2),   ox=2q
        f32x4 a01 = {0.f, 0.f, 0.f, 0.f};    // u=0,             ox=2q+1
        f32x4 a10 = {0.f, 0.f, 0.f, 0.f};    // u=1 (row 2y2+1), ox=2q
        f32x4 a11 = {0.f, 0.f, 0.f, 0.f};    // u=1,             ox=2q+1
        #pragma unroll
        for (int s = 0; s < 6; ++s) {
            AB8 b0, b1;
            #pragma unroll
            for (int m = 0; m < 4; ++m) {
                u32 x0 = lds[vbase[s][m] + q * 65];        // u=0: +q cells
                u32 x1 = lds[vbase[s][m] + (q + 7) * 65];  // u=1: +7+q cells
                if (s == 5) { x0 &= zmask[m]; x1 &= zmask[m]; }
                b0.u[m] = x0; b1.u[m] = x1;
            }
            a00 = __builtin_amdgcn_mfma_f32_16x16x32_f16(wA[s].h, b0.h, a00, 0, 0, 0);
            a01 = __builtin_amdgcn_mfma_f32_16x16x32_f16(wS[s].h, b0.h, a01, 0, 0, 0);
            a10 = __builtin_amdgcn_mfma_f32_16x16x32_f16(wA[s].h, b1.h, a10, 0, 0, 0);
            a11 = __builtin_amdgcn_mfma_f32_16x16x32_f16(wS[s].h, b1.h, a11, 0, 0, 0);
        }
        // fused tanh + S4 reshape-flat pooling (flat f = u*10 + ox, x2 = f>>2)
        #pragma unroll
        for (int r = 0; r < 4; ++r) {
            pool[r][(2 * q) >> 2]      += tact(a00[r] + b3v[r]);
            pool[r][(2 * q + 1) >> 2]  += tact(a01[r] + b3v[r]);
            pool[r][(10 + 2 * q) >> 2] += tact(a10[r] + b3v[r]);
            pool[r][(11 + 2 * q) >> 2] += tact(a11[r] + b3v[r]);
        }
    }

    // S4 affine + tanh, store in R9 s4p format: u32[(oc*5+y2)*3+j][nb]
    const int sG = base + sLocal;
    #pragma unroll
    for (int r = 0; r < 4; ++r) {
        float so[5];
        #pragma unroll
        for (int x2 = 0; x2 < 5; ++x2)
            so[x2] = tact(0.25f * pool[r][x2] * swv[r] + sbv[r]);
        const int ocr = 4 * g + r;
        const size_t gf = (size_t)(ocr * 5 + y2) * 3;
        s4p[(gf + 0) * nb + sG] = packh2(so[0], so[1]);
        s4p[(gf + 1) * nb + sG] = packh2(so[2], so[3]);
        s4p[(gf + 2) * nb + sG] = packh2(so[4], 0.0f);
    }
}

// ---------------- C5: 120-ch GEMV over 240 s4 pairs, grid (nb/256, 12) ------
__global__ __launch_bounds__(256) void k_c5(
    const u32* __restrict__ s4p, const u32* __restrict__ wpk,
    const float* __restrict__ b5, u32* __restrict__ h5p, int nb)
{
    const int sl = blockIdx.x * 256 + threadIdx.x;
    const int chg = blockIdx.y;              // channels chg*10 .. chg*10+9
    const u32* wp = wpk + WPK_W5 + chg * 10 * 240;
    float acc[10];
    #pragma unroll
    for (int c = 0; c < 10; ++c) acc[c] = b5[chg * 10 + c];
    #pragma unroll 4
    for (int i = 0; i < 240; ++i) {
        const u32 v = s4p[(size_t)i * nb + sl];
        #pragma unroll
        for (int c = 0; c < 10; ++c)
            acc[c] = dot2(v, wp[c * 240 + i], acc[c]);   // uniform -> s_load
    }
    #pragma unroll
    for (int j = 0; j < 5; ++j)
        h5p[(size_t)(chg * 5 + j) * nb + sl] =
            packh2(tact(acc[2 * j]), tact(acc[2 * j + 1]));
}

// ---------------- F6: 84-out GEMV over 60 h5 pairs, grid (nb/256, 6) --------
__global__ __launch_bounds__(256) void k_f6(
    const u32* __restrict__ h5p, const u32* __restrict__ wpk,
    const float* __restrict__ f6b, u32* __restrict__ h6p, int nb)
{
    const int sl = blockIdx.x * 256 + threadIdx.x;
    const int og = blockIdx.y;               // outputs og*14 .. og*14+13
    const u32* wp = wpk + WPK_F6 + og * 14 * 60;
    float acc[14];
    #pragma unroll
    for (int o = 0; o < 14; ++o) acc[o] = f6b[og * 14 + o];
    #pragma unroll 4
    for (int i = 0; i < 60; ++i) {
        const u32 v = h5p[(size_t)i * nb + sl];
        #pragma unroll
        for (int o = 0; o < 14; ++o)
            acc[o] = dot2(v, wp[o * 60 + i], acc[o]);    // uniform -> s_load
    }
    #pragma unroll
    for (int j = 0; j < 7; ++j)
        h6p[(size_t)(og * 7 + j) * nb + sl] =
            packh2(tact(acc[2 * j]), tact(acc[2 * j + 1]));
}

// ---------------- RBF head, grid (nb/256, 5): 2 classes per block -----------
__global__ __launch_bounds__(256) void k_rbf(
    const u32* __restrict__ h6p, const float* __restrict__ rbf,
    float* __restrict__ out, int nb)
{
    const int sl = blockIdx.x * 256 + threadIdx.x;
    const int gy = blockIdx.y;
    float hv[84];
    #pragma unroll
    for (int i = 0; i < 42; ++i) {
        const u32 v = h6p[(size_t)i * nb + sl];
        hv[2 * i]     = f16lo(v);
        hv[2 * i + 1] = f16hi(v);
    }
    #pragma unroll
    for (int a = 0; a < 2; ++a) {
        const int c = 2 * gy + a;
        float acc = 0.0f;
        #pragma unroll 4
        for (int i = 0; i < 84; ++i) {
            float d = hv[i] - rbf[c * 84 + i];   // uniform -> s_load
            acc += d * d;
        }
        out[(size_t)sl * 10 + c] = acc;
    }
}

extern "C" void kernel_launch(void* const* d_in, const int* in_sizes, int n_in,
                              void* d_out, int out_size, void* d_ws, size_t ws_size,
                              hipStream_t stream)
{
    const float* x    = (const float*)d_in[0];
    const float* w1   = (const float*)d_in[1];
    const float* b1   = (const float*)d_in[2];
    const float* s2w  = (const float*)d_in[3];
    const float* s2b  = (const float*)d_in[4];
    const float* w3   = (const float*)d_in[5];
    const float* b3   = (const float*)d_in[6];
    const float* s4w  = (const float*)d_in[7];
    const float* s4b  = (const float*)d_in[8];
    const float* w5   = (const float*)d_in[9];
    const float* b5   = (const float*)d_in[10];
    const float* f6w  = (const float*)d_in[11];
    const float* f6b  = (const float*)d_in[12];
    const float* rbfw = (const float*)d_in[13];
    float* out = (float*)d_out;
    char* ws = (char*)d_ws;

    // Weight pack at the tail of d_out (dead until k_rbf; k_rbf never reads
    // it and rewrites every byte of out at the end of each plan/chunk order).
    u32* WPK = (u32*)((char*)d_out +
                      (((size_t)out_size - (size_t)(WPK_N * 4)) & ~(size_t)7));
    k_wpack<<<dim3((WPK_N + 255) / 256), 256, 0, stream>>>(w1, w3, w5, f6w, WPK);

    if (ws_size >= 55312384) {
        // ---- Plan A: full-batch tail (10 dispatches) ----
        u32* S2P = (u32*)(ws);                       // 38,535,168 B (cells)
        u32* XP  = (u32*)(ws + 38535168);            // 16,777,216 B (front)
        u32* S4P = (u32*)(ws + 38535168);            // 15,728,640 B (after front)
        u32* H5P = (u32*)(ws);                       //  3,932,160 B (after c3s4)
        u32* H6P = (u32*)(ws + 4194304);             //  2,752,512 B
        for (int c = 0; c < 2; ++c) {
            k_tr  <<<dim3(128, 16), 256, 0, stream>>>(x + (size_t)c * 8192 * 1024, XP);
            k_c1s2m<<<dim3(128, 14), 256, 0, stream>>>(XP, WPK, b1, s2w, s2b,
                                                       S2P + (size_t)c * 16384,
                                                       8192, 16384);
        }
        k_c3s4m<<<dim3(256, 5), 256, 0, stream>>>(S2P, WPK, b3, s4w, s4b, S4P, 16384);
        k_c5  <<<dim3(64, 12), 256, 0, stream>>>(S4P, WPK, b5, H5P, 16384);
        k_f6  <<<dim3(64, 6), 256, 0, stream>>>(H5P, WPK, f6b, H6P, 16384);
        k_rbf <<<dim3(64, 5), 256, 0, stream>>>(H6P, rbfw, out, 16384);
    } else {
        // ---- Plan B: 2 chunks (13 dispatches) ----
        u32* XP  = (u32*)(ws);                       // 16,777,216 B
        u32* S2P = (u32*)(ws + 16777216);            // 19,267,584 B
        u32* S4P = (u32*)(ws);                       //  7,864,320 B (XP dead)
        u32* H5P = (u32*)(ws + 7864320);             //  1,966,080 B
        u32* H6P = (u32*)(ws + 9830400);             //  1,376,256 B
        for (int c = 0; c < 2; ++c) {
            k_tr  <<<dim3(128, 16), 256, 0, stream>>>(x + (size_t)c * 8192 * 1024, XP);
            k_c1s2m<<<dim3(128, 14), 256, 0, stream>>>(XP, WPK, b1, s2w, s2b,
                                                       S2P, 8192, 8192);
            k_c3s4m<<<dim3(128, 5), 256, 0, stream>>>(S2P, WPK, b3, s4w, s4b, S4P, 8192);
            k_c5  <<<dim3(32, 12), 256, 0, stream>>>(S4P, WPK, b5, H5P, 8192);
            k_f6  <<<dim3(32, 6), 256, 0, stream>>>(H5P, WPK, f6b, H6P, 8192);
            k_rbf <<<dim3(32, 5), 256, 0, stream>>>(H6P, rbfw, out + (size_t)c * 8192 * 10, 8192);
        }
    }
}